// Round 3
// baseline (462.591 us; speedup 1.0000x reference)
//
#include <hip/hip_runtime.h>

#define NN 50000
#define NE 1600000
#define DD 128
#define NL 4
#define NG 512
#define NBUK 196    // dst buckets of 256 nodes: ceil(50000/256)
#define NBLK 196    // edge blocks: ceil(NE/8192)
#define EPB 8192    // edges per block in bucket passes
#define HN (NBUK * NBLK)  // 38416
#define HT 151      // ceil(HN/256)

typedef __attribute__((ext_vector_type(8))) short short8;
typedef __attribute__((ext_vector_type(4))) float floatx4;

__device__ __forceinline__ unsigned short f2bf(float f) {
    unsigned int u = __float_as_uint(f);
    u += 0x7fffu + ((u >> 16) & 1u);
    return (unsigned short)(u >> 16);
}
__device__ __forceinline__ float bf2f(unsigned short u) {
    return __uint_as_float(((unsigned int)u) << 16);
}

// ---------- fp32 -> bf16 convert (layer-0 input) ----------
__global__ __launch_bounds__(256) void cvt_kernel(const float* __restrict__ x,
                                                  unsigned short* __restrict__ xbf) {
    int idx = blockIdx.x * 256 + threadIdx.x;  // one float4 per thread
    float4 f = ((const float4*)x)[idx];
    ushort4 o;
    o.x = f2bf(f.x); o.y = f2bf(f.y); o.z = f2bf(f.z); o.w = f2bf(f.w);
    ((ushort4*)xbf)[idx] = o;
}

// ---------- CSR build: LDS-only counting sort (ZERO global atomics) ----------
// R6/R7: global atomic RMWs execute memory-side on gfx950 (~35 B write-through
// + serialized round trip each, scope hints ignored). Bucket sort, LDS atomics.

// Pass 1: per-(block, bucket) histogram, bucket = dst>>8
__global__ __launch_bounds__(512) void bhist_kernel(const int* __restrict__ dst,
                                                    int* __restrict__ hist) {
    __shared__ int h[NBUK];
    int tid = threadIdx.x;
    for (int i = tid; i < NBUK; i += 512) h[i] = 0;
    __syncthreads();
    int base = blockIdx.x * EPB;
#pragma unroll
    for (int it = 0; it < EPB / 512; it++) {
        int e = base + it * 512 + tid;
        if (e < NE) atomicAdd(&h[dst[e] >> 8], 1);
    }
    __syncthreads();
    for (int i = tid; i < NBUK; i += 512) hist[i * NBLK + blockIdx.x] = h[i];
}

// Pass 2a/2b/2c: exclusive scan of hist[HN] (bucket-major) -> bkoff[HN]
__global__ __launch_bounds__(256) void sum_tiles_kernel(const int* __restrict__ in,
                                                        int* __restrict__ tsum, int n) {
    int i = blockIdx.x * 256 + threadIdx.x;
    __shared__ int s[256];
    s[threadIdx.x] = (i < n) ? in[i] : 0;
    __syncthreads();
    for (int off = 128; off > 0; off >>= 1) {
        if (threadIdx.x < off) s[threadIdx.x] += s[threadIdx.x + off];
        __syncthreads();
    }
    if (threadIdx.x == 0) tsum[blockIdx.x] = s[0];
}

__global__ __launch_bounds__(256) void scan_tiles_kernel(const int* __restrict__ tsum,
                                                         int* __restrict__ toff, int ntiles) {
    int t = threadIdx.x;
    __shared__ int s[256];
    int v = (t < ntiles) ? tsum[t] : 0;
    s[t] = v;
    __syncthreads();
    for (int off = 1; off < 256; off <<= 1) {
        int u = (t >= off) ? s[t - off] : 0;
        __syncthreads();
        s[t] += u;
        __syncthreads();
    }
    if (t < ntiles) toff[t] = s[t] - v;
}

__global__ __launch_bounds__(256) void scan_out_kernel(const int* __restrict__ in,
                                                       const int* __restrict__ toff,
                                                       int* __restrict__ out, int n) {
    int i = blockIdx.x * 256 + threadIdx.x;
    int t = threadIdx.x;
    int v = (i < n) ? in[i] : 0;
    __shared__ int s[256];
    s[t] = v;
    __syncthreads();
    for (int off = 1; off < 256; off <<= 1) {
        int u = (t >= off) ? s[t - off] : 0;
        __syncthreads();
        s[t] += u;
        __syncthreads();
    }
    if (i < n) out[i] = toff[blockIdx.x] + s[t] - v;
}

// Pass 3: scatter edges into bucket-sorted ebuf, PACKED: (src<<8)|(dst&255).
__global__ __launch_bounds__(512) void bscatter_kernel(const int* __restrict__ src,
                                                       const int* __restrict__ dst,
                                                       const int* __restrict__ bkoff,
                                                       int* __restrict__ ebuf) {
    __shared__ int h[NBUK];
    int tid = threadIdx.x;
    for (int i = tid; i < NBUK; i += 512) h[i] = 0;
    __syncthreads();
    int base = blockIdx.x * EPB;
#pragma unroll
    for (int it = 0; it < EPB / 512; it++) {
        int e = base + it * 512 + tid;
        if (e < NE) {
            int d = dst[e];
            int bu = d >> 8;
            int p = atomicAdd(&h[bu], 1);
            ebuf[bkoff[bu * NBLK + blockIdx.x] + p] = (src[e] << 8) | (d & 255);
        }
    }
}

// Pass 4: one block per bucket: LDS histogram over dst&255 -> LDS scan
// -> rowptr for this bucket's nodes + scatter src into final CSR col.
__global__ __launch_bounds__(256) void bucket_csr_kernel(const int* __restrict__ ebuf,
                                                         const int* __restrict__ bkoff,
                                                         int* __restrict__ rowptr,
                                                         int* __restrict__ col) {
    __shared__ int cnt[256], exc[256], c2[256];
    int b = blockIdx.x, tid = threadIdx.x;
    int segstart = bkoff[b * NBLK];
    int segend = (b < NBUK - 1) ? bkoff[(b + 1) * NBLK] : NE;
    cnt[tid] = 0;
    c2[tid] = 0;
    __syncthreads();
    for (int i = segstart + tid; i < segend; i += 256)
        atomicAdd(&cnt[ebuf[i] & 255], 1);
    __syncthreads();
    int v = cnt[tid];
    exc[tid] = v;
    __syncthreads();
    for (int off = 1; off < 256; off <<= 1) {
        int u = (tid >= off) ? exc[tid - off] : 0;
        __syncthreads();
        exc[tid] += u;
        __syncthreads();
    }
    int excl = exc[tid] - v;  // exclusive prefix
    exc[tid] = excl;          // own-slot rewrite; others read only after barrier
    int node = (b << 8) + tid;
    if (node <= NN) rowptr[node] = segstart + excl;
    __syncthreads();
    for (int i = segstart + tid; i < segend; i += 256) {
        int ev = ebuf[i];
        int low = ev & 255;
        int p = atomicAdd(&c2[low], 1);
        col[segstart + exc[low] + p] = ((unsigned)ev) >> 8;
    }
}

// ---------- weight prep: fp32 [l][k][n] -> bf16 transposed [l][n][k] ----------
__global__ __launch_bounds__(256) void prep_kernel(const float* __restrict__ Ws1,
                                                   const float* __restrict__ Ws2,
                                                   unsigned short* __restrict__ W1T,
                                                   unsigned short* __restrict__ W2T) {
    int idx = blockIdx.x * 256 + threadIdx.x;  // [0, NL*DD*DD)
    int l = idx >> 14;
    int rem = idx & 16383;
    int k = rem >> 7;
    int n = rem & 127;
    int o = (l << 14) + (n << 7) + k;
    W1T[o] = f2bf(Ws1[idx]);
    W2T[o] = f2bf(Ws2[idx]);
}

// ---------- aggregation: hpre[i] = x[i] + sum_{j in N(i)} x[j], bf16 in/out ----------
// R3(this session): WAVE-PER-NODE. 64 lanes own one node's 128-elem row
// (1 uint = 2 bf16 per lane; 256 B row = 64 x 4 B coalesced into 4 lines).
// Loop trip = node degree = wave-uniform -> zero intra-wave divergence waste
// (old 16-lane-group model: 4 nodes/wave, E[max deg of 4]/mean ~ 1.18 -> ~18% idle).
// R2 established: fabric-BW-bound at ~154 MB L2-miss/pass; more in-flight is
// neutral; VGPR kept low (~30) for max occupancy.
__global__ __launch_bounds__(256) void agg_kernel(const unsigned short* __restrict__ xbf,
                                                  const int* __restrict__ rowptr,
                                                  const int* __restrict__ col,
                                                  unsigned short* __restrict__ hpre) {
    int wid = threadIdx.x >> 6;   // 4 waves = 4 nodes per block
    int lane = threadIdx.x & 63;
    int node = blockIdx.x * 4 + wid;  // NN = 12500*4 exactly
    const unsigned int* base = (const unsigned int*)xbf;  // 64 uints per row
    size_t roff = (size_t)node * 64 + lane;
    float a0, a1;
    {
        unsigned int v = base[roff];
        a0 = __uint_as_float(v << 16);
        a1 = __uint_as_float(v & 0xFFFF0000u);
    }
    int s = rowptr[node], e = rowptr[node + 1];
    int i = s;
#define ACC(V)                                    \
        a0 += __uint_as_float((V) << 16);         \
        a1 += __uint_as_float((V) & 0xFFFF0000u)
    for (; i + 8 <= e; i += 8) {
        unsigned int v0 = base[(size_t)col[i] * 64 + lane];
        unsigned int v1 = base[(size_t)col[i + 1] * 64 + lane];
        unsigned int v2 = base[(size_t)col[i + 2] * 64 + lane];
        unsigned int v3 = base[(size_t)col[i + 3] * 64 + lane];
        unsigned int v4 = base[(size_t)col[i + 4] * 64 + lane];
        unsigned int v5 = base[(size_t)col[i + 5] * 64 + lane];
        unsigned int v6 = base[(size_t)col[i + 6] * 64 + lane];
        unsigned int v7 = base[(size_t)col[i + 7] * 64 + lane];
        ACC(v0); ACC(v1); ACC(v2); ACC(v3); ACC(v4); ACC(v5); ACC(v6); ACC(v7);
    }
    for (; i < e; i++) {
        unsigned int v = base[(size_t)col[i] * 64 + lane];
        ACC(v);
    }
#undef ACC
    unsigned int o = (unsigned int)f2bf(a0) | ((unsigned int)f2bf(a1) << 16);
    ((unsigned int*)hpre)[roff] = o;
}

// ---------- fused MLP: O = (relu(A@W1^T+b1))@W2^T + b2, one block per 128 rows ----
// R2: 64-row tile regressed (staging is the serial cost; halving tile doubles it).
// Back to 128-row (R1 config) + T14 async-stage: W2 loads ISSUED at kernel start
// into registers, ds_write'd after the post-GEMM1 barrier -> the W2 global-load
// latency hides under W1-stage + GEMM1 + epilogue1 instead of sitting serially
// between the GEMMs. VGPR ~88->~120 (still 2 blocks/CU, LDS-limited at 64 KB).
// Swapped-operand MFMA: mfma(A=W_frag, B=x_frag) -> D[n][m], m = lane&15;
// lane holds 4 consecutive n -> packed 8B uint2 stores. H never touches HBM.
// LDS XOR-swizzle in 16B units: idx = r*128 + (c ^ ((r&7)<<3)) (G4/T2).
__global__ __launch_bounds__(256) void mlp_kernel(const unsigned short* __restrict__ A,
                                                  const unsigned short* __restrict__ W1,
                                                  const float* __restrict__ b1,
                                                  const unsigned short* __restrict__ W2,
                                                  const float* __restrict__ b2,
                                                  unsigned short* __restrict__ O) {
    __shared__ unsigned short Wl[128 * 128];  // 32 KB, holds W1 then W2
    __shared__ unsigned short Hl[128 * 128];  // 32 KB hidden tile
    int tid = threadIdx.x;
    int wg = tid >> 6;
    int lane = tid & 63;
    int quad = lane >> 4;
    int li = lane & 15;
    int mg = wg >> 1, ng = wg & 1;
    int rowb = blockIdx.x * 128;

    // ---- stage W1 ([n][k] bf16, swizzled) ----
    {
        const uint4* wgl = (const uint4*)W1;  // 2048 uint4
#pragma unroll
        for (int it = 0; it < 8; it++) {
            int idx = it * 256 + tid;
            int n = idx >> 4, kc = idx & 15;
            *(uint4*)&Wl[n * 128 + ((kc * 8) ^ ((n & 7) << 3))] = wgl[idx];
        }
    }
    // ---- T14: issue W2 loads NOW; consumed after post-GEMM1 barrier ----
    uint4 w2r[8];
    {
        const uint4* wgl = (const uint4*)W2;
#pragma unroll
        for (int it = 0; it < 8; it++) w2r[it] = wgl[it * 256 + tid];
    }
    __syncthreads();

    floatx4 acc[4][4];
#pragma unroll
    for (int tn = 0; tn < 4; tn++)
#pragma unroll
        for (int mi = 0; mi < 4; mi++) acc[tn][mi] = (floatx4){0.f, 0.f, 0.f, 0.f};

    // ---- GEMM1: D[n][m] = W1 . A^T ----
#pragma unroll
    for (int kk = 0; kk < 4; kk++) {
        int kc = kk * 32 + quad * 8;
        short8 xf[4];
#pragma unroll
        for (int mi = 0; mi < 4; mi++) {
            int ar = rowb + mg * 64 + mi * 16 + li;
            xf[mi] = (ar < NN) ? *(const short8*)(A + (size_t)ar * DD + kc)
                               : (short8){0, 0, 0, 0, 0, 0, 0, 0};
        }
#pragma unroll
        for (int tn = 0; tn < 4; tn++) {
            int wr = ng * 64 + tn * 16 + li;
            short8 wf = *(const short8*)&Wl[wr * 128 + (kc ^ ((wr & 7) << 3))];
#pragma unroll
            for (int mi = 0; mi < 4; mi++)
                acc[tn][mi] = __builtin_amdgcn_mfma_f32_16x16x32_bf16(wf, xf[mi], acc[tn][mi], 0, 0, 0);
        }
    }

    // ---- epilogue 1: +b1, relu, bf16 -> Hl (4 consecutive n per lane = uint2) ----
#pragma unroll
    for (int tn = 0; tn < 4; tn++) {
        float4 bv = ((const float4*)b1)[ng * 16 + tn * 4 + quad];
#pragma unroll
        for (int mi = 0; mi < 4; mi++) {
            int hr = mg * 64 + mi * 16 + li;
            float v0 = fmaxf(acc[tn][mi][0] + bv.x, 0.f);
            float v1 = fmaxf(acc[tn][mi][1] + bv.y, 0.f);
            float v2 = fmaxf(acc[tn][mi][2] + bv.z, 0.f);
            float v3 = fmaxf(acc[tn][mi][3] + bv.w, 0.f);
            uint2 u;
            u.x = (unsigned int)f2bf(v0) | ((unsigned int)f2bf(v1) << 16);
            u.y = (unsigned int)f2bf(v2) | ((unsigned int)f2bf(v3) << 16);
            int c = (ng * 64 + tn * 16 + quad * 4) ^ ((hr & 7) << 3);
            *(uint2*)&Hl[hr * 128 + c] = u;
        }
    }
    __syncthreads();  // Wl(W1) reads done + Hl fully written

    // ---- stage W2 from registers (loads issued at kernel start) ----
    {
#pragma unroll
        for (int it = 0; it < 8; it++) {
            int idx = it * 256 + tid;
            int n = idx >> 4, kc = idx & 15;
            *(uint4*)&Wl[n * 128 + ((kc * 8) ^ ((n & 7) << 3))] = w2r[it];
        }
    }
    __syncthreads();

    // ---- GEMM2: D[n2][m] = W2 . H^T ----
#pragma unroll
    for (int tn = 0; tn < 4; tn++)
#pragma unroll
        for (int mi = 0; mi < 4; mi++) acc[tn][mi] = (floatx4){0.f, 0.f, 0.f, 0.f};

#pragma unroll
    for (int kk = 0; kk < 4; kk++) {
        int kc = kk * 32 + quad * 8;
        short8 hf[4];
#pragma unroll
        for (int mi = 0; mi < 4; mi++) {
            int hr = mg * 64 + mi * 16 + li;
            hf[mi] = *(const short8*)&Hl[hr * 128 + (kc ^ ((hr & 7) << 3))];
        }
#pragma unroll
        for (int tn = 0; tn < 4; tn++) {
            int wr = ng * 64 + tn * 16 + li;
            short8 wf = *(const short8*)&Wl[wr * 128 + (kc ^ ((wr & 7) << 3))];
#pragma unroll
            for (int mi = 0; mi < 4; mi++)
                acc[tn][mi] = __builtin_amdgcn_mfma_f32_16x16x32_bf16(wf, hf[mi], acc[tn][mi], 0, 0, 0);
        }
    }

    // ---- epilogue 2: +b2, bf16 -> global O (8B packed stores) ----
#pragma unroll
    for (int tn = 0; tn < 4; tn++) {
        float4 bv = ((const float4*)b2)[ng * 16 + tn * 4 + quad];
#pragma unroll
        for (int mi = 0; mi < 4; mi++) {
            int m = rowb + mg * 64 + mi * 16 + li;
            if (m < NN) {
                uint2 u;
                u.x = (unsigned int)f2bf(acc[tn][mi][0] + bv.x) |
                      ((unsigned int)f2bf(acc[tn][mi][1] + bv.y) << 16);
                u.y = (unsigned int)f2bf(acc[tn][mi][2] + bv.z) |
                      ((unsigned int)f2bf(acc[tn][mi][3] + bv.w) << 16);
                *(uint2*)&O[(size_t)m * DD + ng * 64 + tn * 16 + quad * 4] = u;
            }
        }
    }
}

// ---------- global add pool: batch sorted -> per-graph contiguous range ----------
__global__ __launch_bounds__(128) void pool_kernel(const unsigned short* __restrict__ x,
                                                   const int* __restrict__ batch,
                                                   float* __restrict__ out) {
    int g = blockIdx.x;
    int lo = 0, hi = NN;
    while (lo < hi) { int mid = (lo + hi) >> 1; if (batch[mid] < g) lo = mid + 1; else hi = mid; }
    int s = lo;
    hi = NN;
    while (lo < hi) { int mid = (lo + hi) >> 1; if (batch[mid] < g + 1) lo = mid + 1; else hi = mid; }
    int e = lo;
    int d = threadIdx.x;
    float acc = 0.f;
    for (int i = s; i < e; i++) acc += bf2f(x[(size_t)i * DD + d]);
    out[g * DD + d] = acc;
}

extern "C" void kernel_launch(void* const* d_in, const int* in_sizes, int n_in,
                              void* d_out, int out_size, void* d_ws, size_t ws_size,
                              hipStream_t stream) {
    const float* x0 = (const float*)d_in[0];
    const int* edge = (const int*)d_in[1];
    const int* batch = (const int*)d_in[2];
    const float* Ws1 = (const float*)d_in[3];
    const float* bs1 = (const float*)d_in[4];
    const float* Ws2 = (const float*)d_in[5];
    const float* bs2 = (const float*)d_in[6];
    float* out = (float*)d_out;
    const int* src = edge;
    const int* dst = edge + NE;

    char* ws = (char*)d_ws;
    size_t off = 0;
    auto alloc = [&](size_t bytes) {
        void* p = ws + off;
        off += (bytes + 255) & ~(size_t)255;
        return p;
    };
    unsigned short* x0bf = (unsigned short*)alloc((size_t)NN * DD * 2);
    unsigned short* xA = (unsigned short*)alloc((size_t)NN * DD * 2);
    unsigned short* xB = (unsigned short*)alloc((size_t)NN * DD * 2);
    unsigned short* hpre = (unsigned short*)alloc((size_t)NN * DD * 2);
    int* col = (int*)alloc((size_t)NE * 4);
    int* ebuf = (int*)alloc((size_t)NE * 4);
    int* hist = (int*)alloc((size_t)HN * 4);
    int* bkoff = (int*)alloc((size_t)HN * 4);
    int* tsum = (int*)alloc((size_t)HT * 4);
    int* toff = (int*)alloc((size_t)HT * 4);
    int* rowptr = (int*)alloc((size_t)(NN + 1) * 4);
    unsigned short* W1T = (unsigned short*)alloc((size_t)NL * DD * DD * 2);
    unsigned short* W2T = (unsigned short*)alloc((size_t)NL * DD * DD * 2);

    cvt_kernel<<<(NN * DD / 4) / 256, 256, 0, stream>>>(x0, x0bf);
    bhist_kernel<<<NBLK, 512, 0, stream>>>(dst, hist);
    sum_tiles_kernel<<<HT, 256, 0, stream>>>(hist, tsum, HN);
    scan_tiles_kernel<<<1, 256, 0, stream>>>(tsum, toff, HT);
    scan_out_kernel<<<HT, 256, 0, stream>>>(hist, toff, bkoff, HN);
    bscatter_kernel<<<NBLK, 512, 0, stream>>>(src, dst, bkoff, ebuf);
    bucket_csr_kernel<<<NBUK, 256, 0, stream>>>(ebuf, bkoff, rowptr, col);
    prep_kernel<<<(NL * DD * DD) / 256, 256, 0, stream>>>(Ws1, Ws2, W1T, W2T);

    const unsigned short* xin = x0bf;
    unsigned short* bufs[2] = {xA, xB};
    const int mlp_grid = (NN + 127) / 128;  // 391
    for (int l = 0; l < NL; l++) {
        agg_kernel<<<NN / 4, 256, 0, stream>>>(xin, rowptr, col, hpre);
        unsigned short* xout = bufs[l & 1];
        mlp_kernel<<<mlp_grid, 256, 0, stream>>>(hpre, W1T + l * DD * DD, bs1 + l * DD,
                                                 W2T + l * DD * DD, bs2 + l * DD, xout);
        xin = xout;
    }
    pool_kernel<<<NG, 128, 0, stream>>>(xin, batch, out);
}

// Round 4
// 436.252 us; speedup vs baseline: 1.0604x; 1.0604x over previous
//
#include <hip/hip_runtime.h>

#define NN 50000
#define NE 1600000
#define DD 128
#define NL 4
#define NG 512
#define BSH 7       // bucket shift: 128 nodes per bucket
#define BMSK 127
#define NBUK 391    // ceil(50000/128)
#define NBLK 196    // edge blocks: ceil(NE/8192)
#define EPB 8192    // edges per block in bucket passes
#define HN (NBUK * NBLK)  // 76636
#define HT 150      // ceil(HN/512)
#define EPT 20      // bucket_csr: max edges per thread (seg<=5120; actual max ~4320)

typedef __attribute__((ext_vector_type(8))) short short8;
typedef __attribute__((ext_vector_type(4))) float floatx4;

__device__ __forceinline__ unsigned short f2bf(float f) {
    unsigned int u = __float_as_uint(f);
    u += 0x7fffu + ((u >> 16) & 1u);
    return (unsigned short)(u >> 16);
}
__device__ __forceinline__ float bf2f(unsigned short u) {
    return __uint_as_float(((unsigned int)u) << 16);
}

// ---------- fp32 -> bf16 convert (layer-0 input) ----------
__global__ __launch_bounds__(256) void cvt_kernel(const float* __restrict__ x,
                                                  unsigned short* __restrict__ xbf) {
    int idx = blockIdx.x * 256 + threadIdx.x;  // one float4 per thread
    float4 f = ((const float4*)x)[idx];
    ushort4 o;
    o.x = f2bf(f.x); o.y = f2bf(f.y); o.z = f2bf(f.z); o.w = f2bf(f.w);
    ((ushort4*)xbf)[idx] = o;
}

// ---------- CSR build: LDS-only counting sort (ZERO global atomics) ----------
// R4(this session): CSR is the hidden ~150+ us sink (each pass < top-5 cutoff).
// 128-node buckets (2x parallelism, half the per-block serial atomics) +
// register-held single-read bucket_csr (pass-1 atomic return IS the rank).

// Pass 1: per-(block, bucket) histogram, bucket = dst>>7
__global__ __launch_bounds__(512) void bhist_kernel(const int* __restrict__ dst,
                                                    int* __restrict__ hist) {
    __shared__ int h[NBUK];
    int tid = threadIdx.x;
    for (int i = tid; i < NBUK; i += 512) h[i] = 0;
    __syncthreads();
    int base = blockIdx.x * EPB;
#pragma unroll
    for (int it = 0; it < EPB / 512; it++) {
        int e = base + it * 512 + tid;
        if (e < NE) atomicAdd(&h[dst[e] >> BSH], 1);
    }
    __syncthreads();
    for (int i = tid; i < NBUK; i += 512) hist[i * NBLK + blockIdx.x] = h[i];
}

// Pass 2a/2b/2c: exclusive scan of hist[HN] (bucket-major) -> bkoff[HN], 512-tiles
__global__ __launch_bounds__(512) void sum_tiles_kernel(const int* __restrict__ in,
                                                        int* __restrict__ tsum, int n) {
    int i = blockIdx.x * 512 + threadIdx.x;
    __shared__ int s[512];
    s[threadIdx.x] = (i < n) ? in[i] : 0;
    __syncthreads();
    for (int off = 256; off > 0; off >>= 1) {
        if (threadIdx.x < off) s[threadIdx.x] += s[threadIdx.x + off];
        __syncthreads();
    }
    if (threadIdx.x == 0) tsum[blockIdx.x] = s[0];
}

__global__ __launch_bounds__(256) void scan_tiles_kernel(const int* __restrict__ tsum,
                                                         int* __restrict__ toff, int ntiles) {
    int t = threadIdx.x;
    __shared__ int s[256];
    int v = (t < ntiles) ? tsum[t] : 0;
    s[t] = v;
    __syncthreads();
    for (int off = 1; off < 256; off <<= 1) {
        int u = (t >= off) ? s[t - off] : 0;
        __syncthreads();
        s[t] += u;
        __syncthreads();
    }
    if (t < ntiles) toff[t] = s[t] - v;
}

__global__ __launch_bounds__(512) void scan_out_kernel(const int* __restrict__ in,
                                                       const int* __restrict__ toff,
                                                       int* __restrict__ out, int n) {
    int i = blockIdx.x * 512 + threadIdx.x;
    int t = threadIdx.x;
    int v = (i < n) ? in[i] : 0;
    __shared__ int s[512];
    s[t] = v;
    __syncthreads();
    for (int off = 1; off < 512; off <<= 1) {
        int u = (t >= off) ? s[t - off] : 0;
        __syncthreads();
        s[t] += u;
        __syncthreads();
    }
    if (i < n) out[i] = toff[blockIdx.x] + s[t] - v;
}

// Pass 3: scatter edges into bucket-sorted ebuf, PACKED: (src<<7)|(dst&127).
__global__ __launch_bounds__(512) void bscatter_kernel(const int* __restrict__ src,
                                                       const int* __restrict__ dst,
                                                       const int* __restrict__ bkoff,
                                                       int* __restrict__ ebuf) {
    __shared__ int h[NBUK];
    int tid = threadIdx.x;
    for (int i = tid; i < NBUK; i += 512) h[i] = 0;
    __syncthreads();
    int base = blockIdx.x * EPB;
#pragma unroll
    for (int it = 0; it < EPB / 512; it++) {
        int e = base + it * 512 + tid;
        if (e < NE) {
            int d = dst[e];
            int bu = d >> BSH;
            int p = atomicAdd(&h[bu], 1);
            ebuf[bkoff[bu * NBLK + blockIdx.x] + p] = (src[e] << BSH) | (d & BMSK);
        }
    }
}

// Pass 4: one block per 128-node bucket. SINGLE read of the segment into
// registers; pass-1 LDS atomic return value is the within-node rank; scan of
// cnt[128] -> rowptr/rowend; scatter from registers. (Old version: 2 atomic
// passes + segment re-read.)
__global__ __launch_bounds__(256) void bucket_csr_kernel(const int* __restrict__ ebuf,
                                                         const int* __restrict__ bkoff,
                                                         int* __restrict__ rowptr,
                                                         int* __restrict__ rowend,
                                                         int* __restrict__ col) {
    __shared__ int cnt[128], exc[128], ebase[128];
    int b = blockIdx.x, tid = threadIdx.x;
    int segstart = bkoff[b * NBLK];
    int segend = (b < NBUK - 1) ? bkoff[(b + 1) * NBLK] : NE;
    if (tid < 128) cnt[tid] = 0;
    __syncthreads();
    int evr[EPT];
    int rnk[EPT];
#pragma unroll
    for (int j = 0; j < EPT; j++) {
        int i = segstart + tid + j * 256;
        if (i < segend) {
            int ev = ebuf[i];
            evr[j] = ev;
            rnk[j] = atomicAdd(&cnt[ev & BMSK], 1);
        } else {
            evr[j] = -1;
        }
    }
    __syncthreads();
    int v = (tid < 128) ? cnt[tid] : 0;
    if (tid < 128) exc[tid] = v;
    __syncthreads();
    for (int off = 1; off < 128; off <<= 1) {
        int u = (tid < 128 && tid >= off) ? exc[tid - off] : 0;
        __syncthreads();
        if (tid < 128) exc[tid] += u;
        __syncthreads();
    }
    if (tid < 128) {
        int excl = exc[tid] - v;  // exclusive prefix
        ebase[tid] = segstart + excl;
        int node = (b << BSH) + tid;
        if (node < NN) {
            rowptr[node] = segstart + excl;
            rowend[node] = segstart + excl + v;
        }
    }
    __syncthreads();
#pragma unroll
    for (int j = 0; j < EPT; j++) {
        if (evr[j] >= 0) {
            int low = evr[j] & BMSK;
            col[ebase[low] + rnk[j]] = ((unsigned)evr[j]) >> BSH;
        }
    }
}

// ---------- weight prep: fp32 [l][k][n] -> bf16 transposed [l][n][k] ----------
__global__ __launch_bounds__(256) void prep_kernel(const float* __restrict__ Ws1,
                                                   const float* __restrict__ Ws2,
                                                   unsigned short* __restrict__ W1T,
                                                   unsigned short* __restrict__ W2T) {
    int idx = blockIdx.x * 256 + threadIdx.x;  // [0, NL*DD*DD)
    int l = idx >> 14;
    int rem = idx & 16383;
    int k = rem >> 7;
    int n = rem & 127;
    int o = (l << 14) + (n << 7) + k;
    W1T[o] = f2bf(Ws1[idx]);
    W2T[o] = f2bf(Ws2[idx]);
}

// ---------- aggregation: hpre[i] = x[i] + sum_{j in N(i)} x[j], bf16 in/out ----------
// R1-exact (best measured: 53.5-53.9 us). R2/R3 established agg is fabric-BW
// bound at ~151-154 MB L2-miss per pass (~3.1 TB/s) — structural floor; x
// (12.8 MB) can't fit a 4 MB XCD-L2, every XCD replicates it. Only change:
// e from rowend[] (CSR now emits rowptr/rowend pairs).
__global__ __launch_bounds__(256) void agg_kernel(const unsigned short* __restrict__ xbf,
                                                  const int* __restrict__ rowptr,
                                                  const int* __restrict__ rowend,
                                                  const int* __restrict__ col,
                                                  unsigned short* __restrict__ hpre) {
    int g = threadIdx.x >> 4;   // 16 node-groups per block
    int lane = threadIdx.x & 15;
    int node = blockIdx.x * 16 + g;  // NN = 3125*16 exactly
    const uint4* base = (const uint4*)xbf;
    float a[8];
    {
        uint4 v = base[node * 16 + lane];
        a[0] = __uint_as_float(v.x << 16); a[1] = __uint_as_float(v.x & 0xFFFF0000u);
        a[2] = __uint_as_float(v.y << 16); a[3] = __uint_as_float(v.y & 0xFFFF0000u);
        a[4] = __uint_as_float(v.z << 16); a[5] = __uint_as_float(v.z & 0xFFFF0000u);
        a[6] = __uint_as_float(v.w << 16); a[7] = __uint_as_float(v.w & 0xFFFF0000u);
    }
    int s = rowptr[node], e = rowend[node];
    int i = s;
    for (; i + 8 <= e; i += 8) {
        uint4 v0 = base[col[i] * 16 + lane];
        uint4 v1 = base[col[i + 1] * 16 + lane];
        uint4 v2 = base[col[i + 2] * 16 + lane];
        uint4 v3 = base[col[i + 3] * 16 + lane];
        uint4 v4 = base[col[i + 4] * 16 + lane];
        uint4 v5 = base[col[i + 5] * 16 + lane];
        uint4 v6 = base[col[i + 6] * 16 + lane];
        uint4 v7 = base[col[i + 7] * 16 + lane];
#define ACC(V)                                                            \
        a[0] += __uint_as_float(V.x << 16); a[1] += __uint_as_float(V.x & 0xFFFF0000u); \
        a[2] += __uint_as_float(V.y << 16); a[3] += __uint_as_float(V.y & 0xFFFF0000u); \
        a[4] += __uint_as_float(V.z << 16); a[5] += __uint_as_float(V.z & 0xFFFF0000u); \
        a[6] += __uint_as_float(V.w << 16); a[7] += __uint_as_float(V.w & 0xFFFF0000u)
        ACC(v0); ACC(v1); ACC(v2); ACC(v3); ACC(v4); ACC(v5); ACC(v6); ACC(v7);
    }
    for (; i < e; i++) {
        uint4 v = base[col[i] * 16 + lane];
        ACC(v);
    }
#undef ACC
    uint4 o;
    o.x = (unsigned int)f2bf(a[0]) | ((unsigned int)f2bf(a[1]) << 16);
    o.y = (unsigned int)f2bf(a[2]) | ((unsigned int)f2bf(a[3]) << 16);
    o.z = (unsigned int)f2bf(a[4]) | ((unsigned int)f2bf(a[5]) << 16);
    o.w = (unsigned int)f2bf(a[6]) | ((unsigned int)f2bf(a[7]) << 16);
    ((uint4*)hpre)[node * 16 + lane] = o;
}

// ---------- fused MLP: O = (relu(A@W1^T+b1))@W2^T + b2, one block per 128 rows ----
// R1-exact (the 437.8 config). R2 64-row tile and R3 T14-prestage both regressed.
// Swapped-operand MFMA: mfma(A=W_frag, B=x_frag) -> D[n][m], m = lane&15;
// lane holds 4 consecutive n -> packed 8B uint2 stores. H never touches HBM.
// LDS XOR-swizzle in 16B units: idx = r*128 + (c ^ ((r&7)<<3)) (G4/T2).
__global__ __launch_bounds__(256) void mlp_kernel(const unsigned short* __restrict__ A,
                                                  const unsigned short* __restrict__ W1,
                                                  const float* __restrict__ b1,
                                                  const unsigned short* __restrict__ W2,
                                                  const float* __restrict__ b2,
                                                  unsigned short* __restrict__ O) {
    __shared__ unsigned short Wl[128 * 128];  // 32 KB, holds W1 then W2
    __shared__ unsigned short Hl[128 * 128];  // 32 KB hidden tile
    int tid = threadIdx.x;
    int wg = tid >> 6;
    int lane = tid & 63;
    int quad = lane >> 4;
    int li = lane & 15;
    int mg = wg >> 1, ng = wg & 1;
    int rowb = blockIdx.x * 128;

    // ---- stage W1 ([n][k] bf16, swizzled) ----
    {
        const uint4* wgl = (const uint4*)W1;  // 2048 uint4
#pragma unroll
        for (int it = 0; it < 8; it++) {
            int idx = it * 256 + tid;
            int n = idx >> 4, kc = idx & 15;
            *(uint4*)&Wl[n * 128 + ((kc * 8) ^ ((n & 7) << 3))] = wgl[idx];
        }
    }
    __syncthreads();

    floatx4 acc[4][4];
#pragma unroll
    for (int tn = 0; tn < 4; tn++)
#pragma unroll
        for (int mi = 0; mi < 4; mi++) acc[tn][mi] = (floatx4){0.f, 0.f, 0.f, 0.f};

    // ---- GEMM1: D[n][m] = W1 . A^T ----
#pragma unroll
    for (int kk = 0; kk < 4; kk++) {
        int kc = kk * 32 + quad * 8;
        short8 xf[4];
#pragma unroll
        for (int mi = 0; mi < 4; mi++) {
            int ar = rowb + mg * 64 + mi * 16 + li;
            xf[mi] = (ar < NN) ? *(const short8*)(A + (size_t)ar * DD + kc)
                               : (short8){0, 0, 0, 0, 0, 0, 0, 0};
        }
#pragma unroll
        for (int tn = 0; tn < 4; tn++) {
            int wr = ng * 64 + tn * 16 + li;
            short8 wf = *(const short8*)&Wl[wr * 128 + (kc ^ ((wr & 7) << 3))];
#pragma unroll
            for (int mi = 0; mi < 4; mi++)
                acc[tn][mi] = __builtin_amdgcn_mfma_f32_16x16x32_bf16(wf, xf[mi], acc[tn][mi], 0, 0, 0);
        }
    }

    // ---- epilogue 1: +b1, relu, bf16 -> Hl (4 consecutive n per lane = uint2) ----
#pragma unroll
    for (int tn = 0; tn < 4; tn++) {
        float4 bv = ((const float4*)b1)[ng * 16 + tn * 4 + quad];
#pragma unroll
        for (int mi = 0; mi < 4; mi++) {
            int hr = mg * 64 + mi * 16 + li;
            float v0 = fmaxf(acc[tn][mi][0] + bv.x, 0.f);
            float v1 = fmaxf(acc[tn][mi][1] + bv.y, 0.f);
            float v2 = fmaxf(acc[tn][mi][2] + bv.z, 0.f);
            float v3 = fmaxf(acc[tn][mi][3] + bv.w, 0.f);
            uint2 u;
            u.x = (unsigned int)f2bf(v0) | ((unsigned int)f2bf(v1) << 16);
            u.y = (unsigned int)f2bf(v2) | ((unsigned int)f2bf(v3) << 16);
            int c = (ng * 64 + tn * 16 + quad * 4) ^ ((hr & 7) << 3);
            *(uint2*)&Hl[hr * 128 + c] = u;
        }
    }
    __syncthreads();  // Wl(W1) reads done + Hl fully written

    // ---- stage W2 over Wl ----
    {
        const uint4* wgl = (const uint4*)W2;
#pragma unroll
        for (int it = 0; it < 8; it++) {
            int idx = it * 256 + tid;
            int n = idx >> 4, kc = idx & 15;
            *(uint4*)&Wl[n * 128 + ((kc * 8) ^ ((n & 7) << 3))] = wgl[idx];
        }
    }
    __syncthreads();

    // ---- GEMM2: D[n2][m] = W2 . H^T ----
#pragma unroll
    for (int tn = 0; tn < 4; tn++)
#pragma unroll
        for (int mi = 0; mi < 4; mi++) acc[tn][mi] = (floatx4){0.f, 0.f, 0.f, 0.f};

#pragma unroll
    for (int kk = 0; kk < 4; kk++) {
        int kc = kk * 32 + quad * 8;
        short8 hf[4];
#pragma unroll
        for (int mi = 0; mi < 4; mi++) {
            int hr = mg * 64 + mi * 16 + li;
            hf[mi] = *(const short8*)&Hl[hr * 128 + (kc ^ ((hr & 7) << 3))];
        }
#pragma unroll
        for (int tn = 0; tn < 4; tn++) {
            int wr = ng * 64 + tn * 16 + li;
            short8 wf = *(const short8*)&Wl[wr * 128 + (kc ^ ((wr & 7) << 3))];
#pragma unroll
            for (int mi = 0; mi < 4; mi++)
                acc[tn][mi] = __builtin_amdgcn_mfma_f32_16x16x32_bf16(wf, hf[mi], acc[tn][mi], 0, 0, 0);
        }
    }

    // ---- epilogue 2: +b2, bf16 -> global O (8B packed stores) ----
#pragma unroll
    for (int tn = 0; tn < 4; tn++) {
        float4 bv = ((const float4*)b2)[ng * 16 + tn * 4 + quad];
#pragma unroll
        for (int mi = 0; mi < 4; mi++) {
            int m = rowb + mg * 64 + mi * 16 + li;
            if (m < NN) {
                uint2 u;
                u.x = (unsigned int)f2bf(acc[tn][mi][0] + bv.x) |
                      ((unsigned int)f2bf(acc[tn][mi][1] + bv.y) << 16);
                u.y = (unsigned int)f2bf(acc[tn][mi][2] + bv.z) |
                      ((unsigned int)f2bf(acc[tn][mi][3] + bv.w) << 16);
                *(uint2*)&O[(size_t)m * DD + ng * 64 + tn * 16 + quad * 4] = u;
            }
        }
    }
}

// ---------- global add pool: batch sorted -> per-graph contiguous range ----------
__global__ __launch_bounds__(128) void pool_kernel(const unsigned short* __restrict__ x,
                                                   const int* __restrict__ batch,
                                                   float* __restrict__ out) {
    int g = blockIdx.x;
    int lo = 0, hi = NN;
    while (lo < hi) { int mid = (lo + hi) >> 1; if (batch[mid] < g) lo = mid + 1; else hi = mid; }
    int s = lo;
    hi = NN;
    while (lo < hi) { int mid = (lo + hi) >> 1; if (batch[mid] < g + 1) lo = mid + 1; else hi = mid; }
    int e = lo;
    int d = threadIdx.x;
    float acc = 0.f;
    for (int i = s; i < e; i++) acc += bf2f(x[(size_t)i * DD + d]);
    out[g * DD + d] = acc;
}

extern "C" void kernel_launch(void* const* d_in, const int* in_sizes, int n_in,
                              void* d_out, int out_size, void* d_ws, size_t ws_size,
                              hipStream_t stream) {
    const float* x0 = (const float*)d_in[0];
    const int* edge = (const int*)d_in[1];
    const int* batch = (const int*)d_in[2];
    const float* Ws1 = (const float*)d_in[3];
    const float* bs1 = (const float*)d_in[4];
    const float* Ws2 = (const float*)d_in[5];
    const float* bs2 = (const float*)d_in[6];
    float* out = (float*)d_out;
    const int* src = edge;
    const int* dst = edge + NE;

    char* ws = (char*)d_ws;
    size_t off = 0;
    auto alloc = [&](size_t bytes) {
        void* p = ws + off;
        off += (bytes + 255) & ~(size_t)255;
        return p;
    };
    unsigned short* x0bf = (unsigned short*)alloc((size_t)NN * DD * 2);
    unsigned short* xA = (unsigned short*)alloc((size_t)NN * DD * 2);
    unsigned short* xB = (unsigned short*)alloc((size_t)NN * DD * 2);
    unsigned short* hpre = (unsigned short*)alloc((size_t)NN * DD * 2);
    int* col = (int*)alloc((size_t)NE * 4);
    int* ebuf = (int*)alloc((size_t)NE * 4);
    int* hist = (int*)alloc((size_t)HN * 4);
    int* bkoff = (int*)alloc((size_t)HN * 4);
    int* tsum = (int*)alloc((size_t)HT * 4);
    int* toff = (int*)alloc((size_t)HT * 4);
    int* rowptr = (int*)alloc((size_t)(NN + 1) * 4);
    int* rowend = (int*)alloc((size_t)NN * 4);
    unsigned short* W1T = (unsigned short*)alloc((size_t)NL * DD * DD * 2);
    unsigned short* W2T = (unsigned short*)alloc((size_t)NL * DD * DD * 2);

    cvt_kernel<<<(NN * DD / 4) / 256, 256, 0, stream>>>(x0, x0bf);
    bhist_kernel<<<NBLK, 512, 0, stream>>>(dst, hist);
    sum_tiles_kernel<<<HT, 512, 0, stream>>>(hist, tsum, HN);
    scan_tiles_kernel<<<1, 256, 0, stream>>>(tsum, toff, HT);
    scan_out_kernel<<<HT, 512, 0, stream>>>(hist, toff, bkoff, HN);
    bscatter_kernel<<<NBLK, 512, 0, stream>>>(src, dst, bkoff, ebuf);
    bucket_csr_kernel<<<NBUK, 256, 0, stream>>>(ebuf, bkoff, rowptr, rowend, col);
    prep_kernel<<<(NL * DD * DD) / 256, 256, 0, stream>>>(Ws1, Ws2, W1T, W2T);

    const unsigned short* xin = x0bf;
    unsigned short* bufs[2] = {xA, xB};
    const int mlp_grid = (NN + 127) / 128;  // 391
    for (int l = 0; l < NL; l++) {
        agg_kernel<<<NN / 16, 256, 0, stream>>>(xin, rowptr, rowend, col, hpre);
        unsigned short* xout = bufs[l & 1];
        mlp_kernel<<<mlp_grid, 256, 0, stream>>>(hpre, W1T + l * DD * DD, bs1 + l * DD,
                                                 W2T + l * DD * DD, bs2 + l * DD, xout);
        xin = xout;
    }
    pool_kernel<<<NG, 128, 0, stream>>>(xin, batch, out);
}